// Round 1
// baseline (1353.466 us; speedup 1.0000x reference)
//
#include <hip/hip_runtime.h>

typedef unsigned short u16;
typedef unsigned int u32;
typedef __attribute__((ext_vector_type(4))) u16 u16x4;
typedef __attribute__((ext_vector_type(8))) __bf16 bf16x8;
typedef __attribute__((ext_vector_type(4))) float floatx4;

#define INV_BN 0.9999950000374997f
#define IN0 2176

__device__ __forceinline__ float b2f(u16 u) {
  return __builtin_bit_cast(float, (u32)u << 16);
}
__device__ __forceinline__ u16 f2b(float f) {
  u32 x = __builtin_bit_cast(u32, f);
  return (u16)((x + 0x7fffu + ((x >> 16) & 1u)) >> 16);
}

// ---------------- embedding gather: [B,F] ids -> X0[:, 0:2048] bf16 ----------------
__global__ __launch_bounds__(256) void embed_gather(
    const int* __restrict__ cat, const float* __restrict__ table,
    u16* __restrict__ X0) {
  int idx = blockIdx.x * 256 + threadIdx.x;  // over B*F*32 float4-groups
  int d4 = idx & 31;
  int bf = idx >> 5;
  int f = bf & 15;
  int b = bf >> 4;
  long row = (long)cat[bf] + (long)f * 50000;
  float4 v = *((const float4*)(table + row * 128) + d4);
  u16x4 o = {f2b(v.x), f2b(v.y), f2b(v.z), f2b(v.w)};
  *(u16x4*)(X0 + (long)b * IN0 + f * 128 + d4 * 4) = o;
}

// ---------------- numerical linear: [B,63]@[63,128]+b -> X0[:, 2048:2176] ----------
__global__ __launch_bounds__(256) void num_linear(
    const float* __restrict__ xn, const float* __restrict__ W,
    const float* __restrict__ bias, u16* __restrict__ X0) {
  int idx = blockIdx.x * 256 + threadIdx.x;  // B*128
  int o = idx & 127;
  int b = idx >> 7;
  float acc = bias[o];
  const float* xr = xn + b * 63;
  for (int k = 0; k < 63; k++) acc = fmaf(xr[k], W[k * 128 + o], acc);
  X0[(long)b * IN0 + 2048 + o] = f2b(acc);
}

// ---------------- weight repack: src [E][K][O] f32 -> dst bf16 [nBase+e*O+o][K], col-scaled by INV*g
__global__ __launch_bounds__(256) void repack_w(
    const float* __restrict__ src, const float* __restrict__ gsc,
    u16* __restrict__ dst, int K, int O, int nBase) {
  __shared__ float tile[32][33];
  int e = blockIdx.z;
  int k0 = blockIdx.x * 32, o0 = blockIdx.y * 32;
  int tx = threadIdx.x & 31, ty = threadIdx.x >> 5;
  const float* S = src + (long)e * K * O;
#pragma unroll
  for (int r = 0; r < 32; r += 8)
    tile[ty + r][tx] = S[(long)(k0 + ty + r) * O + o0 + tx];
  __syncthreads();
#pragma unroll
  for (int r = 0; r < 32; r += 8) {
    int o = o0 + ty + r;
    float s = INV_BN * gsc[e * O + o];
    dst[(long)(nBase + e * O + o) * K + k0 + tx] = f2b(tile[tx][ty + r] * s);
  }
}

// ---------------- fused BN bias: out = b*INV*g + be ----------------
__global__ __launch_bounds__(256) void fuse_bias(
    const float* __restrict__ b, const float* __restrict__ g,
    const float* __restrict__ be, float* __restrict__ out, int n) {
  int i = blockIdx.x * 256 + threadIdx.x;
  if (i < n) out[i] = b[i] * INV_BN * g[i] + be[i];
}

// ---------------- m97-style bf16 GEMM: C[m][n] = relu(sum_k A[m][k]*Bw[n][k] + bias[n]) ----
// A [M][K] bf16 row-major, Bw [N][K] bf16 (n-major), C [M][N] bf16. 128x128 tile, BK=32.
__global__ __launch_bounds__(256) void gemm_bf16(
    const u16* __restrict__ A, long aStride,
    const u16* __restrict__ Bw, long bStride,
    u16* __restrict__ C, long cStride,
    const float* __restrict__ bias, long biasStride,
    int M, int N, int K) {
  int z = blockIdx.z;
  A += (long)z * aStride;
  Bw += (long)z * bStride;
  C += (long)z * cStride;
  bias += (long)z * biasStride;
  __shared__ u16 As[128 * 32];
  __shared__ u16 Bs[128 * 32];
  int tid = threadIdx.x;
  int m0 = blockIdx.x * 128, n0 = blockIdx.y * 128;
  int l = tid & 63, w = tid >> 6;
  int wm = (w >> 1) * 64, wn = (w & 1) * 64;

  const u16* aS0 = A + (long)(m0 + (tid >> 2)) * K + (tid & 3) * 8;
  const u16* aS1 = A + (long)(m0 + 64 + (tid >> 2)) * K + (tid & 3) * 8;
  const u16* bS0 = Bw + (long)(n0 + (tid >> 2)) * K + (tid & 3) * 8;
  const u16* bS1 = Bw + (long)(n0 + 64 + (tid >> 2)) * K + (tid & 3) * 8;
  u16* aD0 = As + tid * 8;
  u16* aD1 = As + (256 + tid) * 8;
  u16* bD0 = Bs + tid * 8;
  u16* bD1 = Bs + (256 + tid) * 8;

  floatx4 acc[4][4] = {};

  int aOff[4], bOff[4];
#pragma unroll
  for (int i = 0; i < 4; i++) {
    aOff[i] = (wm + i * 16 + (l & 15)) * 32 + (l >> 4) * 8;
    bOff[i] = (wn + i * 16 + (l & 15)) * 32 + (l >> 4) * 8;
  }

  for (int k0 = 0; k0 < K; k0 += 32) {
    __builtin_amdgcn_global_load_lds((const __attribute__((address_space(1))) u16*)aS0,
                                     (__attribute__((address_space(3))) u16*)aD0, 16, 0, 0);
    __builtin_amdgcn_global_load_lds((const __attribute__((address_space(1))) u16*)aS1,
                                     (__attribute__((address_space(3))) u16*)aD1, 16, 0, 0);
    __builtin_amdgcn_global_load_lds((const __attribute__((address_space(1))) u16*)bS0,
                                     (__attribute__((address_space(3))) u16*)bD0, 16, 0, 0);
    __builtin_amdgcn_global_load_lds((const __attribute__((address_space(1))) u16*)bS1,
                                     (__attribute__((address_space(3))) u16*)bD1, 16, 0, 0);
    aS0 += 32; aS1 += 32; bS0 += 32; bS1 += 32;
    __syncthreads();
    bf16x8 af[4], bfr[4];
#pragma unroll
    for (int i = 0; i < 4; i++) af[i] = *(const bf16x8*)(As + aOff[i]);
#pragma unroll
    for (int j = 0; j < 4; j++) bfr[j] = *(const bf16x8*)(Bs + bOff[j]);
#pragma unroll
    for (int i = 0; i < 4; i++)
#pragma unroll
      for (int j = 0; j < 4; j++)
        acc[i][j] = __builtin_amdgcn_mfma_f32_16x16x32_bf16(af[i], bfr[j], acc[i][j], 0, 0, 0);
    __syncthreads();
  }

  int cn = n0 + wn + (l & 15);
  int rm = m0 + wm + ((l >> 4) << 2);
#pragma unroll
  for (int j = 0; j < 4; j++) {
    float bv = bias[cn + j * 16];
#pragma unroll
    for (int i = 0; i < 4; i++)
#pragma unroll
      for (int r = 0; r < 4; r++) {
        float v = fmaxf(acc[i][j][r] + bv, 0.f);
        C[(long)(rm + i * 16 + r) * N + cn + j * 16] = f2b(v);
      }
  }
}

// ---------------- layer-0 gates: logits [B][56]: c<32 task gates (t=c/16,j=c%16), c>=32 shared (24)
__global__ __launch_bounds__(256) void gates0_kernel(
    const u16* __restrict__ X0, const float* __restrict__ tgW,
    const float* __restrict__ tgb, const float* __restrict__ sgW,
    const float* __restrict__ sgb, float* __restrict__ logits) {
  __shared__ u16 xs[8 * IN0];  // 34 KB
  int tid = threadIdx.x;
  int bBase = blockIdx.x * 8;
  const u16x4* src = (const u16x4*)(X0 + (long)bBase * IN0);
  u16x4* dst = (u16x4*)xs;
  for (int i = tid; i < 8 * IN0 / 4; i += 256) dst[i] = src[i];
  __syncthreads();
  int w = tid >> 6, l = tid & 63;
  if (l < 56) {
    const float* Wc;
    int stride;
    float bias;
    if (l < 32) {
      int t = l >> 4, j = l & 15;
      Wc = tgW + (long)t * IN0 * 16 + j;
      stride = 16;
      bias = tgb[t * 16 + j];
    } else {
      Wc = sgW + (l - 32);
      stride = 24;
      bias = sgb[l - 32];
    }
    float a0 = bias, a1 = bias;
    const u16* x0 = xs + (w * 2) * IN0;
    const u16* x1 = x0 + IN0;
    for (int k = 0; k < IN0; k++) {
      float wv = Wc[(long)k * stride];
      a0 = fmaf(wv, b2f(x0[k]), a0);
      a1 = fmaf(wv, b2f(x1[k]), a1);
    }
    float* outp = logits + (long)(bBase + w * 2) * 56 + l;
    outp[0] = a0;
    outp[56] = a1;
  }
}

// ---------------- layer-0 softmax + mix: E0 [B][24*512] -> X1 [3][B][512] (t0,t1,shared)
__global__ __launch_bounds__(256) void mix0_kernel(
    const float* __restrict__ logits, const u16* __restrict__ E0,
    u16* __restrict__ X1) {
  int b = blockIdx.x, tid = threadIdx.x;
  __shared__ float gw[56];
  if (tid < 3) {
    int base = (tid == 0) ? 0 : (tid == 1) ? 16 : 32;
    int cnt = (tid == 2) ? 24 : 16;
    const float* lg = logits + (long)b * 56 + base;
    float mx = -1e30f;
    for (int i = 0; i < cnt; i++) mx = fmaxf(mx, lg[i]);
    float sum = 0.f;
    for (int i = 0; i < cnt; i++) sum += __expf(lg[i] - mx);
    float inv = 1.f / sum;
    for (int i = 0; i < cnt; i++) gw[base + i] = __expf(lg[i] - mx) * inv;
  }
  __syncthreads();
  const u16* row = E0 + (long)b * 12288;
#pragma unroll
  for (int half = 0; half < 2; half++) {
    int o = tid + half * 256;
    float t0 = 0.f, t1 = 0.f, s = 0.f;
#pragma unroll
    for (int e = 0; e < 8; e++) {
      float v0 = b2f(row[e * 512 + o]);          // t0 own experts (cols 0..7)
      float v1 = b2f(row[(8 + e) * 512 + o]);    // t1 own experts (cols 8..15)
      float vs = b2f(row[(16 + e) * 512 + o]);   // shared experts (cols 16..23)
      t0 = fmaf(gw[e], v0, t0);       t0 = fmaf(gw[8 + e], vs, t0);
      t1 = fmaf(gw[16 + e], v1, t1);  t1 = fmaf(gw[24 + e], vs, t1);
      s = fmaf(gw[32 + e], v0, s);
      s = fmaf(gw[40 + e], v1, s);
      s = fmaf(gw[48 + e], vs, s);
    }
    X1[((long)(0 * 4096 + b)) * 512 + o] = f2b(t0);
    X1[((long)(1 * 4096 + b)) * 512 + o] = f2b(t1);
    X1[((long)(2 * 4096 + b)) * 512 + o] = f2b(s);
  }
}

// ---------------- layer-1 gates: logits1 [B][32], input X1[t][b][512] -------------
__global__ __launch_bounds__(256) void gates1_kernel(
    const u16* __restrict__ X1, const float* __restrict__ tgW,
    const float* __restrict__ tgb, float* __restrict__ logits) {
  __shared__ u16 xs[2 * 16 * 512];  // 32 KB
  int tid = threadIdx.x;
  int bBase = blockIdx.x * 16;
  u16x4* dst = (u16x4*)xs;
  for (int i = tid; i < 2 * 16 * 128; i += 256) {
    int t = i >> 11;
    int rem = i & 2047;
    dst[i] = *(const u16x4*)(X1 + ((long)(t * 4096 + bBase)) * 512 + rem * 4);
  }
  __syncthreads();
  int w = tid >> 6, l = tid & 63;
  if (l < 32) {
    int t = l >> 4, j = l & 15;
    const float* Wc = tgW + (long)t * 512 * 16 + j;
    float bias = tgb[t * 16 + j];
    float a0 = bias, a1 = bias, a2 = bias, a3 = bias;
    const u16* xb = xs + (t * 16 + w * 4) * 512;
    for (int k = 0; k < 512; k++) {
      float wv = Wc[k * 16];
      a0 = fmaf(wv, b2f(xb[k]), a0);
      a1 = fmaf(wv, b2f(xb[512 + k]), a1);
      a2 = fmaf(wv, b2f(xb[1024 + k]), a2);
      a3 = fmaf(wv, b2f(xb[1536 + k]), a3);
    }
    float* outp = logits + (long)(bBase + w * 4) * 32 + l;
    outp[0] = a0; outp[32] = a1; outp[64] = a2; outp[96] = a3;
  }
}

// ---------------- layer-1 softmax + mix: E1 [3][B][2048] -> X2 [2][B][256] --------
__global__ __launch_bounds__(256) void mix1_kernel(
    const float* __restrict__ logits, const u16* __restrict__ E1,
    u16* __restrict__ X2) {
  int b = blockIdx.x, tid = threadIdx.x;
  __shared__ float gw[32];
  if (tid < 2) {
    const float* lg = logits + (long)b * 32 + tid * 16;
    float mx = -1e30f;
    for (int i = 0; i < 16; i++) mx = fmaxf(mx, lg[i]);
    float sum = 0.f;
    for (int i = 0; i < 16; i++) sum += __expf(lg[i] - mx);
    float inv = 1.f / sum;
    for (int i = 0; i < 16; i++) gw[tid * 16 + i] = __expf(lg[i] - mx) * inv;
  }
  __syncthreads();
  int o = tid;
  const u16* r0 = E1 + ((long)(0 * 4096 + b)) * 2048;
  const u16* r1 = E1 + ((long)(1 * 4096 + b)) * 2048;
  const u16* rs = E1 + ((long)(2 * 4096 + b)) * 2048;
  float t0 = 0.f, t1 = 0.f;
#pragma unroll
  for (int e = 0; e < 8; e++) {
    float vs = b2f(rs[e * 256 + o]);
    t0 = fmaf(gw[e], b2f(r0[e * 256 + o]), t0);
    t0 = fmaf(gw[8 + e], vs, t0);
    t1 = fmaf(gw[16 + e], b2f(r1[e * 256 + o]), t1);
    t1 = fmaf(gw[24 + e], vs, t1);
  }
  X2[((long)(0 * 4096 + b)) * 256 + o] = f2b(t0);
  X2[((long)(1 * 4096 + b)) * 256 + o] = f2b(t1);
}

// ---------------- towers: [256]->BN relu[128]->BN relu[64]->[1]->sigmoid ----------
__global__ __launch_bounds__(256) void towers_kernel(
    const u16* __restrict__ X2,
    const float* __restrict__ W0, const float* __restrict__ b0,
    const float* __restrict__ g0, const float* __restrict__ be0,
    const float* __restrict__ W1, const float* __restrict__ b1,
    const float* __restrict__ g1, const float* __restrict__ be1,
    const float* __restrict__ W2, const float* __restrict__ b2,
    float* __restrict__ out) {
  int t = blockIdx.y;
  int bBase = blockIdx.x * 32;
  int tid = threadIdx.x;
  __shared__ u16 xs[32 * 256];
  __shared__ u16 h1[32 * 128];
  __shared__ u16 h2[32 * 64];
  {
    u16x4* dst = (u16x4*)xs;
    const u16x4* src = (const u16x4*)(X2 + ((long)(t * 4096 + bBase)) * 256);
    for (int i = tid; i < 32 * 64; i += 256) dst[i] = src[i];
  }
  __syncthreads();
  const float* w0 = W0 + (long)t * 256 * 128;
#pragma unroll
  for (int it = 0; it < 16; it++) {
    int idx = it * 256 + tid;
    int o = idx & 127, r = idx >> 7;
    float acc = 0.f;
    const u16* xr = xs + r * 256;
    for (int k = 0; k < 256; k++) acc = fmaf(b2f(xr[k]), w0[k * 128 + o], acc);
    acc = fmaxf((acc + b0[t * 128 + o]) * INV_BN * g0[t * 128 + o] + be0[t * 128 + o], 0.f);
    h1[r * 128 + o] = f2b(acc);
  }
  __syncthreads();
  const float* w1 = W1 + (long)t * 128 * 64;
#pragma unroll
  for (int it = 0; it < 8; it++) {
    int idx = it * 256 + tid;
    int o = idx & 63, r = idx >> 6;
    float acc = 0.f;
    const u16* xr = h1 + r * 128;
    for (int k = 0; k < 128; k++) acc = fmaf(b2f(xr[k]), w1[k * 64 + o], acc);
    acc = fmaxf((acc + b1[t * 64 + o]) * INV_BN * g1[t * 64 + o] + be1[t * 64 + o], 0.f);
    h2[r * 64 + o] = f2b(acc);
  }
  __syncthreads();
  if (tid < 32) {
    const float* w2 = W2 + t * 64;
    float acc = b2[t];
    const u16* xr = h2 + tid * 64;
    for (int k = 0; k < 64; k++) acc = fmaf(b2f(xr[k]), w2[k], acc);
    out[t * 4096 + bBase + tid] = 1.f / (1.f + __expf(-acc));
  }
}

extern "C" void kernel_launch(void* const* d_in, const int* in_sizes, int n_in,
                              void* d_out, int out_size, void* d_ws, size_t ws_size,
                              hipStream_t stream) {
  const int* cat = (const int*)d_in[0];
  const float* numx = (const float*)d_in[1];
  const float* table = (const float*)d_in[2];
  const float* numW = (const float*)d_in[3];
  const float* numb = (const float*)d_in[4];
  const float* se0W = (const float*)d_in[5];
  const float* se0b = (const float*)d_in[6];
  const float* se0g = (const float*)d_in[7];
  const float* se0be = (const float*)d_in[8];
  const float* te0W = (const float*)d_in[9];
  const float* te0b = (const float*)d_in[10];
  const float* te0g = (const float*)d_in[11];
  const float* te0be = (const float*)d_in[12];
  const float* tg0W = (const float*)d_in[13];
  const float* tg0b = (const float*)d_in[14];
  const float* sg0W = (const float*)d_in[15];
  const float* sg0b = (const float*)d_in[16];
  const float* se1W = (const float*)d_in[17];
  const float* se1b = (const float*)d_in[18];
  const float* se1g = (const float*)d_in[19];
  const float* se1be = (const float*)d_in[20];
  const float* te1W = (const float*)d_in[21];
  const float* te1b = (const float*)d_in[22];
  const float* te1g = (const float*)d_in[23];
  const float* te1be = (const float*)d_in[24];
  const float* tg1W = (const float*)d_in[25];
  const float* tg1b = (const float*)d_in[26];
  const float* tw0W = (const float*)d_in[27];
  const float* tw0b = (const float*)d_in[28];
  const float* tw0g = (const float*)d_in[29];
  const float* tw0be = (const float*)d_in[30];
  const float* tw1W = (const float*)d_in[31];
  const float* tw1b = (const float*)d_in[32];
  const float* tw1g = (const float*)d_in[33];
  const float* tw1be = (const float*)d_in[34];
  const float* twoW = (const float*)d_in[35];
  const float* twob = (const float*)d_in[36];
  float* out = (float*)d_out;

  char* p = (char*)d_ws;
  u16* X0 = (u16*)p;    p += (size_t)4096 * 2176 * 2;
  u16* W0 = (u16*)p;    p += (size_t)12288 * 2176 * 2;
  float* bias0 = (float*)p; p += (size_t)12288 * 4;
  u16* E0 = (u16*)p;    p += (size_t)4096 * 12288 * 2;
  float* lg0 = (float*)p;   p += (size_t)4096 * 56 * 4;
  u16* X1 = (u16*)p;    p += (size_t)3 * 4096 * 512 * 2;
  u16* W1 = (u16*)p;    p += (size_t)3 * 2048 * 512 * 2;
  float* bias1 = (float*)p; p += (size_t)3 * 2048 * 4;
  u16* E1 = (u16*)p;    p += (size_t)3 * 4096 * 2048 * 2;
  float* lg1 = (float*)p;   p += (size_t)4096 * 32 * 4;
  u16* X2 = (u16*)p;    p += (size_t)2 * 4096 * 256 * 2;

  // build X0 = [cat_emb | num_emb] in bf16
  embed_gather<<<8192, 256, 0, stream>>>(cat, table, X0);
  num_linear<<<2048, 256, 0, stream>>>(numx, numW, numb, X0);

  // repack expert weights (BN gamma folded in), n-major bf16
  repack_w<<<dim3(68, 16, 16), 256, 0, stream>>>(te0W, te0g, W0, 2176, 512, 0);
  repack_w<<<dim3(68, 16, 8), 256, 0, stream>>>(se0W, se0g, W0, 2176, 512, 8192);
  repack_w<<<dim3(16, 8, 8), 256, 0, stream>>>(te1W, te1g, W1, 512, 256, 0);
  repack_w<<<dim3(16, 8, 8), 256, 0, stream>>>(te1W + (size_t)8 * 512 * 256, te1g + 8 * 256, W1, 512, 256, 2048);
  repack_w<<<dim3(16, 8, 8), 256, 0, stream>>>(se1W, se1g, W1, 512, 256, 4096);
  fuse_bias<<<32, 256, 0, stream>>>(te0b, te0g, te0be, bias0, 8192);
  fuse_bias<<<16, 256, 0, stream>>>(se0b, se0g, se0be, bias0 + 8192, 4096);
  fuse_bias<<<8, 256, 0, stream>>>(te1b, te1g, te1be, bias1, 2048);
  fuse_bias<<<8, 256, 0, stream>>>(te1b + 2048, te1g + 2048, te1be + 2048, bias1 + 2048, 2048);
  fuse_bias<<<8, 256, 0, stream>>>(se1b, se1g, se1be, bias1 + 4096, 2048);

  // PLE layer 0: one big GEMM (all 24 experts share input X0)
  gemm_bf16<<<dim3(32, 96, 1), 256, 0, stream>>>(X0, 0, W0, 0, E0, 0, bias0, 0,
                                                 4096, 12288, 2176);
  gates0_kernel<<<512, 256, 0, stream>>>(X0, tg0W, tg0b, sg0W, sg0b, lg0);
  mix0_kernel<<<4096, 256, 0, stream>>>(lg0, E0, X1);

  // PLE layer 1: 3 batched GEMMs (t0 / t1 / shared inputs)
  gemm_bf16<<<dim3(32, 16, 3), 256, 0, stream>>>(
      X1, (long)4096 * 512, W1, (long)2048 * 512, E1, (long)4096 * 2048,
      bias1, 2048, 4096, 2048, 512);
  gates1_kernel<<<256, 256, 0, stream>>>(X1, tg1W, tg1b, lg1);
  mix1_kernel<<<4096, 256, 0, stream>>>(lg1, E1, X2);

  // towers + sigmoid
  towers_kernel<<<dim3(128, 2), 256, 0, stream>>>(
      X2, tw0W, tw0b, tw0g, tw0be, tw1W, tw1b, tw1g, tw1be, twoW, twob, out);
}

// Round 2
// 1053.587 us; speedup vs baseline: 1.2846x; 1.2846x over previous
//
#include <hip/hip_runtime.h>

typedef unsigned short u16;
typedef unsigned int u32;
typedef __attribute__((ext_vector_type(4))) u16 u16x4;
typedef __attribute__((ext_vector_type(8))) __bf16 bf16x8;
typedef __attribute__((ext_vector_type(4))) float floatx4;

#define INV_BN 0.9999950000374997f
#define IN0 2176
#define N0EXT 12416  // 12288 expert cols + 56 gate cols + 72 pad
#define N1EXT 2176   // 2048 expert cols + 16 gate cols + 112 pad

__device__ __forceinline__ float b2f(u16 u) {
  return __builtin_bit_cast(float, (u32)u << 16);
}
__device__ __forceinline__ u16 f2b(float f) {
  u32 x = __builtin_bit_cast(u32, f);
  return (u16)((x + 0x7fffu + ((x >> 16) & 1u)) >> 16);
}

// ---------------- embedding gather: [B,F] ids -> X0[:, 0:2048] bf16 ----------------
__global__ __launch_bounds__(256) void embed_gather(
    const int* __restrict__ cat, const float* __restrict__ table,
    u16* __restrict__ X0) {
  int idx = blockIdx.x * 256 + threadIdx.x;  // over B*F*32 float4-groups
  int d4 = idx & 31;
  int bf = idx >> 5;
  int f = bf & 15;
  int b = bf >> 4;
  long row = (long)cat[bf] + (long)f * 50000;
  float4 v = *((const float4*)(table + row * 128) + d4);
  u16x4 o = {f2b(v.x), f2b(v.y), f2b(v.z), f2b(v.w)};
  *(u16x4*)(X0 + (long)b * IN0 + f * 128 + d4 * 4) = o;
}

// ---------------- numerical linear: [B,63]@[63,128]+b -> X0[:, 2048:2176] ----------
__global__ __launch_bounds__(256) void num_linear(
    const float* __restrict__ xn, const float* __restrict__ W,
    const float* __restrict__ bias, u16* __restrict__ X0) {
  int idx = blockIdx.x * 256 + threadIdx.x;  // B*128
  int o = idx & 127;
  int b = idx >> 7;
  float acc = bias[o];
  const float* xr = xn + b * 63;
  for (int k = 0; k < 63; k++) acc = fmaf(xr[k], W[k * 128 + o], acc);
  X0[(long)b * IN0 + 2048 + o] = f2b(acc);
}

// ---------------- weight repack: src [E][K][O] f32 -> dst bf16 [nBase+e*O+o][K], col-scaled by INV*g
__global__ __launch_bounds__(256) void repack_w(
    const float* __restrict__ src, const float* __restrict__ gsc,
    u16* __restrict__ dst, int K, int O, int nBase) {
  __shared__ float tile[32][33];
  int e = blockIdx.z;
  int k0 = blockIdx.x * 32, o0 = blockIdx.y * 32;
  int tx = threadIdx.x & 31, ty = threadIdx.x >> 5;
  const float* S = src + (long)e * K * O;
#pragma unroll
  for (int r = 0; r < 32; r += 8)
    tile[ty + r][tx] = S[(long)(k0 + ty + r) * O + o0 + tx];
  __syncthreads();
#pragma unroll
  for (int r = 0; r < 32; r += 8) {
    int o = o0 + ty + r;
    float s = INV_BN * gsc[e * O + o];
    dst[(long)(nBase + e * O + o) * K + k0 + tx] = f2b(tile[tx][ty + r] * s);
  }
}

// ---------------- gate-weight repack, layer 0: rows 12288..12415 of W0 -------------
// g<32: task gates (t=g>>4, j=g&15) from tg0W [2][2176][16]; 32<=g<56: sg0W [2176][24]; else 0.
__global__ __launch_bounds__(256) void repack_gates0(
    const float* __restrict__ tgW, const float* __restrict__ tgb,
    const float* __restrict__ sgW, const float* __restrict__ sgb,
    u16* __restrict__ W0, float* __restrict__ bias0) {
  int g = blockIdx.x;  // 0..127
  u16* dst = W0 + (long)(12288 + g) * IN0;
  for (int k = threadIdx.x; k < IN0; k += 256) {
    float v;
    if (g < 32) {
      int t = g >> 4, j = g & 15;
      v = tgW[(long)t * IN0 * 16 + k * 16 + j];
    } else if (g < 56) {
      v = sgW[k * 24 + (g - 32)];
    } else {
      v = 0.f;
    }
    dst[k] = f2b(v);
  }
  if (threadIdx.x == 0)
    bias0[12288 + g] = g < 32 ? tgb[g] : (g < 56 ? sgb[g - 32] : 0.f);
}

// ---------------- gate-weight repack, layer 1: rows 2048..2175 of each z-block ----
__global__ __launch_bounds__(256) void repack_gates1(
    const float* __restrict__ tgW, const float* __restrict__ tgb,
    u16* __restrict__ W1, float* __restrict__ bias1) {
  int g = blockIdx.x;  // 0..127
  int z = blockIdx.y;  // 0..2
  u16* dst = W1 + (long)z * N1EXT * 512 + (long)(2048 + g) * 512;
  for (int k = threadIdx.x; k < 512; k += 256) {
    float v = (z < 2 && g < 16) ? tgW[(long)z * 512 * 16 + k * 16 + g] : 0.f;
    dst[k] = f2b(v);
  }
  if (threadIdx.x == 0)
    bias1[z * N1EXT + 2048 + g] = (z < 2 && g < 16) ? tgb[z * 16 + g] : 0.f;
}

// ---------------- tower layer-1 weight repack: [2][128][64] -> TW1 [2][128][128] ---
__global__ __launch_bounds__(128) void repack_tw1(
    const float* __restrict__ W, const float* __restrict__ g,
    const float* __restrict__ b, const float* __restrict__ be,
    u16* __restrict__ TW1, float* __restrict__ biasT1) {
  int n = blockIdx.x;  // 0..127 (output col, real <64)
  int z = blockIdx.y;
  int k = threadIdx.x;  // 0..127
  float v = 0.f;
  if (n < 64) v = W[(long)z * 128 * 64 + k * 64 + n] * INV_BN * g[z * 64 + n];
  TW1[(long)z * 128 * 128 + n * 128 + k] = f2b(v);
  if (k == 0)
    biasT1[z * 128 + n] =
        (n < 64) ? b[z * 64 + n] * INV_BN * g[z * 64 + n] + be[z * 64 + n] : 0.f;
}

// ---------------- fused BN bias: out = b*INV*g + be ----------------
__global__ __launch_bounds__(256) void fuse_bias(
    const float* __restrict__ b, const float* __restrict__ g,
    const float* __restrict__ be, float* __restrict__ out, int n) {
  int i = blockIdx.x * 256 + threadIdx.x;
  if (i < n) out[i] = b[i] * INV_BN * g[i] + be[i];
}

// ---------------- m97-style bf16 GEMM with LDS chunk swizzle + relu cutoff --------
// A [M][K] bf16 row-major, Bw [N][K] bf16 (n-major), C [M][N] bf16.
// C[m][n] = (n<reluN ? relu : id)(sum_k A.B + bias[n]). 128x128 tile, BK=32.
// LDS swizzle: physical 16B-chunk c of row r holds global chunk q = (c - (r>>1)) & 3,
// giving each 16-lane b128 read phase a full 8-bank-group spread (2-way = free).
__global__ __launch_bounds__(256) void gemm_bf16(
    const u16* __restrict__ A, long aStride,
    const u16* __restrict__ Bw, long bStride,
    u16* __restrict__ C, long cStride,
    const float* __restrict__ bias, long biasStride,
    int M, int N, int K, int reluN) {
  int z = blockIdx.z;
  A += (long)z * aStride;
  Bw += (long)z * bStride;
  C += (long)z * cStride;
  bias += (long)z * biasStride;
  __shared__ u16 As[128 * 32];
  __shared__ u16 Bs[128 * 32];
  int tid = threadIdx.x;
  int m0 = blockIdx.x * 128, n0 = blockIdx.y * 128;
  int l = tid & 63, w = tid >> 6;
  int wm = (w >> 1) * 64, wn = (w & 1) * 64;

  // store side: lane tid writes 16B to slot tid (row=tid>>2, phys chunk=tid&3);
  // fetch the permuted global chunk qa so reads below are conflict-free.
  int qa = ((tid & 3) - (tid >> 3)) & 3;
  const u16* aS0 = A + (long)(m0 + (tid >> 2)) * K + qa * 8;
  const u16* aS1 = A + (long)(m0 + 64 + (tid >> 2)) * K + qa * 8;
  const u16* bS0 = Bw + (long)(n0 + (tid >> 2)) * K + qa * 8;
  const u16* bS1 = Bw + (long)(n0 + 64 + (tid >> 2)) * K + qa * 8;
  u16* aD0 = As + tid * 8;
  u16* aD1 = As + (256 + tid) * 8;
  u16* bD0 = Bs + tid * 8;
  u16* bD1 = Bs + (256 + tid) * 8;

  floatx4 acc[4][4] = {};

  int aOff[4], bOff[4];
  int q = l >> 4;
#pragma unroll
  for (int i = 0; i < 4; i++) {
    int Ra = wm + i * 16 + (l & 15);
    int Rb = wn + i * 16 + (l & 15);
    aOff[i] = Ra * 32 + ((q + (Ra >> 1)) & 3) * 8;
    bOff[i] = Rb * 32 + ((q + (Rb >> 1)) & 3) * 8;
  }

  for (int k0 = 0; k0 < K; k0 += 32) {
    __builtin_amdgcn_global_load_lds((const __attribute__((address_space(1))) u16*)aS0,
                                     (__attribute__((address_space(3))) u16*)aD0, 16, 0, 0);
    __builtin_amdgcn_global_load_lds((const __attribute__((address_space(1))) u16*)aS1,
                                     (__attribute__((address_space(3))) u16*)aD1, 16, 0, 0);
    __builtin_amdgcn_global_load_lds((const __attribute__((address_space(1))) u16*)bS0,
                                     (__attribute__((address_space(3))) u16*)bD0, 16, 0, 0);
    __builtin_amdgcn_global_load_lds((const __attribute__((address_space(1))) u16*)bS1,
                                     (__attribute__((address_space(3))) u16*)bD1, 16, 0, 0);
    aS0 += 32; aS1 += 32; bS0 += 32; bS1 += 32;
    __syncthreads();
    bf16x8 af[4], bfr[4];
#pragma unroll
    for (int i = 0; i < 4; i++) af[i] = *(const bf16x8*)(As + aOff[i]);
#pragma unroll
    for (int j = 0; j < 4; j++) bfr[j] = *(const bf16x8*)(Bs + bOff[j]);
#pragma unroll
    for (int i = 0; i < 4; i++)
#pragma unroll
      for (int j = 0; j < 4; j++)
        acc[i][j] = __builtin_amdgcn_mfma_f32_16x16x32_bf16(af[i], bfr[j], acc[i][j], 0, 0, 0);
    __syncthreads();
  }

  int cn = n0 + wn + (l & 15);
  int rm = m0 + wm + ((l >> 4) << 2);
#pragma unroll
  for (int j = 0; j < 4; j++) {
    int col = cn + j * 16;
    float bv = bias[col];
    bool doRelu = col < reluN;
#pragma unroll
    for (int i = 0; i < 4; i++)
#pragma unroll
      for (int r = 0; r < 4; r++) {
        float v = acc[i][j][r] + bv;
        v = doRelu ? fmaxf(v, 0.f) : v;
        C[(long)(rm + i * 16 + r) * N + col] = f2b(v);
      }
  }
}

// ---------------- layer-0 softmax + mix: E0 [B][N0EXT] -> X1 [3][B][512] ----------
// logits are bf16 in E0 cols 12288..12343: 0..15 t0, 16..31 t1, 32..55 shared.
__global__ __launch_bounds__(256) void mix0_kernel(
    const u16* __restrict__ E0, u16* __restrict__ X1) {
  int b = blockIdx.x, tid = threadIdx.x;
  __shared__ float gw[56];
  const u16* row = E0 + (long)b * N0EXT;
  if (tid < 3) {
    int base = (tid == 0) ? 0 : (tid == 1) ? 16 : 32;
    int cnt = (tid == 2) ? 24 : 16;
    const u16* lg = row + 12288 + base;
    float mx = -1e30f;
    for (int i = 0; i < cnt; i++) mx = fmaxf(mx, b2f(lg[i]));
    float sum = 0.f;
    for (int i = 0; i < cnt; i++) {
      float e = __expf(b2f(lg[i]) - mx);
      gw[base + i] = e;
      sum += e;
    }
    float inv = 1.f / sum;
    for (int i = 0; i < cnt; i++) gw[base + i] *= inv;
  }
  __syncthreads();
#pragma unroll
  for (int half = 0; half < 2; half++) {
    int o = tid + half * 256;
    float t0 = 0.f, t1 = 0.f, s = 0.f;
#pragma unroll
    for (int e = 0; e < 8; e++) {
      float v0 = b2f(row[e * 512 + o]);          // t0 own experts (cols 0..7)
      float v1 = b2f(row[(8 + e) * 512 + o]);    // t1 own experts (cols 8..15)
      float vs = b2f(row[(16 + e) * 512 + o]);   // shared experts (cols 16..23)
      t0 = fmaf(gw[e], v0, t0);       t0 = fmaf(gw[8 + e], vs, t0);
      t1 = fmaf(gw[16 + e], v1, t1);  t1 = fmaf(gw[24 + e], vs, t1);
      s = fmaf(gw[32 + e], v0, s);
      s = fmaf(gw[40 + e], v1, s);
      s = fmaf(gw[48 + e], vs, s);
    }
    X1[((long)(0 * 4096 + b)) * 512 + o] = f2b(t0);
    X1[((long)(1 * 4096 + b)) * 512 + o] = f2b(t1);
    X1[((long)(2 * 4096 + b)) * 512 + o] = f2b(s);
  }
}

// ---------------- layer-1 softmax + mix: E1 [3][B][N1EXT] -> X2 [2][B][256] -------
// logits bf16 in E1[t] cols 2048..2063.
__global__ __launch_bounds__(256) void mix1_kernel(
    const u16* __restrict__ E1, u16* __restrict__ X2) {
  int b = blockIdx.x, tid = threadIdx.x;
  __shared__ float gw[32];
  if (tid < 2) {
    const u16* lg = E1 + ((long)(tid * 4096 + b)) * N1EXT + 2048;
    float mx = -1e30f;
    for (int i = 0; i < 16; i++) mx = fmaxf(mx, b2f(lg[i]));
    float sum = 0.f;
    for (int i = 0; i < 16; i++) {
      float e = __expf(b2f(lg[i]) - mx);
      gw[tid * 16 + i] = e;
      sum += e;
    }
    float inv = 1.f / sum;
    for (int i = 0; i < 16; i++) gw[tid * 16 + i] *= inv;
  }
  __syncthreads();
  int o = tid;
  const u16* r0 = E1 + ((long)(0 * 4096 + b)) * N1EXT;
  const u16* r1 = E1 + ((long)(1 * 4096 + b)) * N1EXT;
  const u16* rs = E1 + ((long)(2 * 4096 + b)) * N1EXT;
  float t0 = 0.f, t1 = 0.f;
#pragma unroll
  for (int e = 0; e < 8; e++) {
    float vs = b2f(rs[e * 256 + o]);
    t0 = fmaf(gw[e], b2f(r0[e * 256 + o]), t0);
    t0 = fmaf(gw[8 + e], vs, t0);
    t1 = fmaf(gw[16 + e], b2f(r1[e * 256 + o]), t1);
    t1 = fmaf(gw[24 + e], vs, t1);
  }
  X2[((long)(0 * 4096 + b)) * 256 + o] = f2b(t0);
  X2[((long)(1 * 4096 + b)) * 256 + o] = f2b(t1);
}

// ---------------- final: out[t][b] = sigmoid(dot(H2[t][b][0:64], twoW[t]) + twob[t])
__global__ __launch_bounds__(256) void final_kernel(
    const u16* __restrict__ H2, const float* __restrict__ twoW,
    const float* __restrict__ twob, float* __restrict__ out) {
  int idx = blockIdx.x * 256 + threadIdx.x;  // 8192
  int t = idx >> 12, b = idx & 4095;
  const u16* xr = H2 + ((long)(t * 4096 + b)) * 128;
  const float* wc = twoW + t * 64;
  float acc = twob[t];
  for (int k = 0; k < 64; k++) acc = fmaf(b2f(xr[k]), wc[k], acc);
  out[t * 4096 + b] = 1.f / (1.f + __expf(-acc));
}

extern "C" void kernel_launch(void* const* d_in, const int* in_sizes, int n_in,
                              void* d_out, int out_size, void* d_ws, size_t ws_size,
                              hipStream_t stream) {
  const int* cat = (const int*)d_in[0];
  const float* numx = (const float*)d_in[1];
  const float* table = (const float*)d_in[2];
  const float* numW = (const float*)d_in[3];
  const float* numb = (const float*)d_in[4];
  const float* se0W = (const float*)d_in[5];
  const float* se0b = (const float*)d_in[6];
  const float* se0g = (const float*)d_in[7];
  const float* se0be = (const float*)d_in[8];
  const float* te0W = (const float*)d_in[9];
  const float* te0b = (const float*)d_in[10];
  const float* te0g = (const float*)d_in[11];
  const float* te0be = (const float*)d_in[12];
  const float* tg0W = (const float*)d_in[13];
  const float* tg0b = (const float*)d_in[14];
  const float* sg0W = (const float*)d_in[15];
  const float* sg0b = (const float*)d_in[16];
  const float* se1W = (const float*)d_in[17];
  const float* se1b = (const float*)d_in[18];
  const float* se1g = (const float*)d_in[19];
  const float* se1be = (const float*)d_in[20];
  const float* te1W = (const float*)d_in[21];
  const float* te1b = (const float*)d_in[22];
  const float* te1g = (const float*)d_in[23];
  const float* te1be = (const float*)d_in[24];
  const float* tg1W = (const float*)d_in[25];
  const float* tg1b = (const float*)d_in[26];
  const float* tw0W = (const float*)d_in[27];
  const float* tw0b = (const float*)d_in[28];
  const float* tw0g = (const float*)d_in[29];
  const float* tw0be = (const float*)d_in[30];
  const float* tw1W = (const float*)d_in[31];
  const float* tw1b = (const float*)d_in[32];
  const float* tw1g = (const float*)d_in[33];
  const float* tw1be = (const float*)d_in[34];
  const float* twoW = (const float*)d_in[35];
  const float* twob = (const float*)d_in[36];
  float* out = (float*)d_out;

  char* p = (char*)d_ws;
  u16* X0 = (u16*)p;        p += (size_t)4096 * IN0 * 2;
  u16* W0 = (u16*)p;        p += (size_t)N0EXT * IN0 * 2;
  float* bias0 = (float*)p; p += (size_t)N0EXT * 4;
  u16* X1 = (u16*)p;        p += (size_t)3 * 4096 * 512 * 2;
  u16* W1 = (u16*)p;        p += (size_t)3 * N1EXT * 512 * 2;
  float* bias1 = (float*)p; p += (size_t)3 * N1EXT * 4;
  u16* X2 = (u16*)p;        p += (size_t)2 * 4096 * 256 * 2;
  u16* TW0 = (u16*)p;       p += (size_t)2 * 128 * 256 * 2;
  float* biasT0 = (float*)p; p += (size_t)256 * 4;
  u16* TW1 = (u16*)p;       p += (size_t)2 * 128 * 128 * 2;
  float* biasT1 = (float*)p; p += (size_t)256 * 4;
  // big region, reused across phases: E0 -> E1 -> (H1, H2)
  u16* E0 = (u16*)p;  // 4096*N0EXT
  u16* E1 = (u16*)p;  // 3*4096*N1EXT  (E0 dead after mix0)
  u16* H1 = (u16*)p;  // 2*4096*128    (E1 dead after mix1)
  u16* H2 = H1 + (size_t)2 * 4096 * 128;

  // build X0 = [cat_emb | num_emb] in bf16
  embed_gather<<<8192, 256, 0, stream>>>(cat, table, X0);
  num_linear<<<2048, 256, 0, stream>>>(numx, numW, numb, X0);

  // repack expert weights (BN gamma folded), n-major bf16; gates appended as extra rows
  repack_w<<<dim3(68, 16, 16), 256, 0, stream>>>(te0W, te0g, W0, IN0, 512, 0);
  repack_w<<<dim3(68, 16, 8), 256, 0, stream>>>(se0W, se0g, W0, IN0, 512, 8192);
  repack_gates0<<<128, 256, 0, stream>>>(tg0W, tg0b, sg0W, sg0b, W0, bias0);
  repack_w<<<dim3(16, 8, 8), 256, 0, stream>>>(te1W, te1g, W1, 512, 256, 0);
  repack_w<<<dim3(16, 8, 8), 256, 0, stream>>>(te1W + (size_t)8 * 512 * 256, te1g + 8 * 256,
                                               W1, 512, 256, N1EXT);
  repack_w<<<dim3(16, 8, 8), 256, 0, stream>>>(se1W, se1g, W1, 512, 256, 2 * N1EXT);
  repack_gates1<<<dim3(128, 3), 256, 0, stream>>>(tg1W, tg1b, W1, bias1);
  fuse_bias<<<32, 256, 0, stream>>>(te0b, te0g, te0be, bias0, 8192);
  fuse_bias<<<16, 256, 0, stream>>>(se0b, se0g, se0be, bias0 + 8192, 4096);
  fuse_bias<<<8, 256, 0, stream>>>(te1b, te1g, te1be, bias1, 2048);
  fuse_bias<<<8, 256, 0, stream>>>(te1b + 2048, te1g + 2048, te1be + 2048, bias1 + N1EXT, 2048);
  fuse_bias<<<8, 256, 0, stream>>>(se1b, se1g, se1be, bias1 + 2 * N1EXT, 2048);
  // tower weights
  repack_w<<<dim3(8, 4, 2), 256, 0, stream>>>(tw0W, tw0g, TW0, 256, 128, 0);
  fuse_bias<<<1, 256, 0, stream>>>(tw0b, tw0g, tw0be, biasT0, 256);
  repack_tw1<<<dim3(128, 2), 128, 0, stream>>>(tw1W, tw1g, tw1b, tw1be, TW1, biasT1);

  // PLE layer 0: one big GEMM (24 experts + 56 gate cols, shared input X0)
  gemm_bf16<<<dim3(32, 97, 1), 256, 0, stream>>>(X0, 0, W0, 0, E0, 0, bias0, 0,
                                                 4096, N0EXT, IN0, 12288);
  mix0_kernel<<<4096, 256, 0, stream>>>(E0, X1);

  // PLE layer 1: 3 batched GEMMs (t0 / t1 / shared), gate cols appended
  gemm_bf16<<<dim3(32, 17, 3), 256, 0, stream>>>(
      X1, (long)4096 * 512, W1, (long)N1EXT * 512, E1, (long)4096 * N1EXT,
      bias1, N1EXT, 4096, N1EXT, 512, 2048);
  mix1_kernel<<<4096, 256, 0, stream>>>(E1, X2);

  // towers as GEMMs: [256->128] relu, [128->64(pad128)] relu, then 64-dot sigmoid
  gemm_bf16<<<dim3(32, 1, 2), 256, 0, stream>>>(
      X2, (long)4096 * 256, TW0, (long)128 * 256, H1, (long)4096 * 128,
      biasT0, 128, 4096, 128, 256, 128);
  gemm_bf16<<<dim3(32, 1, 2), 256, 0, stream>>>(
      H1, (long)4096 * 128, TW1, (long)128 * 128, H2, (long)4096 * 128,
      biasT1, 128, 4096, 128, 128, 128);
  final_kernel<<<32, 256, 0, stream>>>(H2, twoW, twob, out);
}

// Round 3
// 972.101 us; speedup vs baseline: 1.3923x; 1.0838x over previous
//
#include <hip/hip_runtime.h>

typedef unsigned short u16;
typedef unsigned int u32;
typedef __attribute__((ext_vector_type(4))) u16 u16x4;
typedef __attribute__((ext_vector_type(8))) __bf16 bf16x8;
typedef __attribute__((ext_vector_type(4))) float floatx4;

#define INV_BN 0.9999950000374997f
#define IN0 2176
#define N0EXT 12416  // 12288 expert cols + 56 gate cols + 72 pad
#define N1EXT 2176   // 2048 expert cols + 16 gate cols + 112 pad

__device__ __forceinline__ float b2f(u16 u) {
  return __builtin_bit_cast(float, (u32)u << 16);
}
__device__ __forceinline__ u16 f2b(float f) {
  u32 x = __builtin_bit_cast(u32, f);
  return (u16)((x + 0x7fffu + ((x >> 16) & 1u)) >> 16);
}

// ---------------- input build: embed gather + numerical linear -> X0 ---------------
__global__ __launch_bounds__(256) void input_build(
    const int* __restrict__ cat, const float* __restrict__ table,
    const float* __restrict__ xn, const float* __restrict__ W,
    const float* __restrict__ bias, u16* __restrict__ X0) {
  int x = blockIdx.x, tid = threadIdx.x;
  if (x < 8192) {
    int idx = x * 256 + tid;  // over B*F*32 float4-groups
    int d4 = idx & 31;
    int bf = idx >> 5;
    int f = bf & 15;
    int b = bf >> 4;
    long row = (long)cat[bf] + (long)f * 50000;
    float4 v = *((const float4*)(table + row * 128) + d4);
    u16x4 o = {f2b(v.x), f2b(v.y), f2b(v.z), f2b(v.w)};
    *(u16x4*)(X0 + (long)b * IN0 + f * 128 + d4 * 4) = o;
  } else {
    int idx = (x - 8192) * 256 + tid;  // B*128
    int o = idx & 127;
    int b = idx >> 7;
    float acc = bias[o];
    const float* xr = xn + b * 63;
    for (int k = 0; k < 63; k++) acc = fmaf(xr[k], W[k * 128 + o], acc);
    X0[(long)b * IN0 + 2048 + o] = f2b(acc);
  }
}

// ---------------- all expert-weight repacks in one launch --------------------------
// src [E][K][O] f32 -> dst bf16 row (nBase+e*O+o), k-contiguous, col-scaled by INV*g.
__global__ __launch_bounds__(256) void repack_w_all(
    const float* __restrict__ te0W, const float* __restrict__ te0g,
    const float* __restrict__ se0W, const float* __restrict__ se0g,
    const float* __restrict__ te1W, const float* __restrict__ te1g,
    const float* __restrict__ se1W, const float* __restrict__ se1g,
    const float* __restrict__ tw0W, const float* __restrict__ tw0g,
    u16* __restrict__ W0, u16* __restrict__ W1, u16* __restrict__ TW0) {
  int z = blockIdx.z;
  const float *src, *gsc;
  u16* dst;
  int K, O, nBase, e, xm, ym;
  if (z < 16) {
    e = z; src = te0W; gsc = te0g; dst = W0; K = 2176; O = 512; nBase = 0; xm = 68; ym = 16;
  } else if (z < 24) {
    e = z - 16; src = se0W; gsc = se0g; dst = W0; K = 2176; O = 512; nBase = 8192; xm = 68; ym = 16;
  } else if (z < 40) {
    e = z - 24; src = te1W; gsc = te1g; dst = W1; K = 512; O = 256;
    nBase = (e < 8) ? 0 : (N1EXT - 2048); xm = 16; ym = 8;
  } else if (z < 48) {
    e = z - 40; src = se1W; gsc = se1g; dst = W1; K = 512; O = 256; nBase = 2 * N1EXT; xm = 16; ym = 8;
  } else {
    e = z - 48; src = tw0W; gsc = tw0g; dst = TW0; K = 256; O = 128; nBase = 0; xm = 8; ym = 4;
  }
  if (blockIdx.x >= (u32)xm || blockIdx.y >= (u32)ym) return;
  __shared__ float tile[32][33];
  int k0 = blockIdx.x * 32, o0 = blockIdx.y * 32;
  int tx = threadIdx.x & 31, ty = threadIdx.x >> 5;
  const float* S = src + (long)e * K * O;
#pragma unroll
  for (int r = 0; r < 32; r += 8)
    tile[ty + r][tx] = S[(long)(k0 + ty + r) * O + o0 + tx];
  __syncthreads();
#pragma unroll
  for (int r = 0; r < 32; r += 8) {
    int o = o0 + ty + r;
    float s = INV_BN * gsc[e * O + o];
    dst[(long)(nBase + e * O + o) * K + k0 + tx] = f2b(tile[tx][ty + r] * s);
  }
}

// ---------------- all small setup work in one launch -------------------------------
__global__ __launch_bounds__(256) void setup_small(
    const float* __restrict__ tg0W, const float* __restrict__ tg0b,
    const float* __restrict__ sg0W, const float* __restrict__ sg0b,
    const float* __restrict__ tg1W, const float* __restrict__ tg1b,
    const float* __restrict__ te0b, const float* __restrict__ te0g, const float* __restrict__ te0be,
    const float* __restrict__ se0b, const float* __restrict__ se0g, const float* __restrict__ se0be,
    const float* __restrict__ te1b, const float* __restrict__ te1g, const float* __restrict__ te1be,
    const float* __restrict__ se1b, const float* __restrict__ se1g, const float* __restrict__ se1be,
    const float* __restrict__ tw0b, const float* __restrict__ tw0g, const float* __restrict__ tw0be,
    const float* __restrict__ tw1W, const float* __restrict__ tw1b,
    const float* __restrict__ tw1g, const float* __restrict__ tw1be,
    u16* __restrict__ W0, u16* __restrict__ W1, u16* __restrict__ TW1,
    float* __restrict__ bias0, float* __restrict__ bias1,
    float* __restrict__ biasT0, float* __restrict__ biasT1) {
  int x = blockIdx.x, tid = threadIdx.x;
  if (x < 128) {  // layer-0 gate rows (W0 rows 12288..12415)
    int g = x;
    u16* dst = W0 + (long)(12288 + g) * IN0;
    for (int k = tid; k < IN0; k += 256) {
      float v;
      if (g < 32) {
        int t = g >> 4, j = g & 15;
        v = tg0W[(long)t * IN0 * 16 + k * 16 + j];
      } else if (g < 56) {
        v = sg0W[k * 24 + (g - 32)];
      } else {
        v = 0.f;
      }
      dst[k] = f2b(v);
    }
    if (tid == 0)
      bias0[12288 + g] = g < 32 ? tg0b[g] : (g < 56 ? sg0b[g - 32] : 0.f);
  } else if (x < 512) {  // layer-1 gate rows
    int i = x - 128;
    int z = i >> 7, g = i & 127;
    u16* dst = W1 + (long)z * N1EXT * 512 + (long)(2048 + g) * 512;
    for (int k = tid; k < 512; k += 256) {
      float v = (z < 2 && g < 16) ? tg1W[(long)z * 512 * 16 + k * 16 + g] : 0.f;
      dst[k] = f2b(v);
    }
    if (tid == 0)
      bias1[z * N1EXT + 2048 + g] = (z < 2 && g < 16) ? tg1b[z * 16 + g] : 0.f;
  } else if (x < 640) {  // tower layer-1 weight repack [2][128k][64o] -> [2][128n][128k]
    int idx = (x - 512) * 256 + tid;  // [0, 32768)
    int z = idx >> 14, rem = idx & 16383, n = rem >> 7, k = rem & 127;
    float v = 0.f;
    if (n < 64) v = tw1W[(long)z * 128 * 64 + k * 64 + n] * INV_BN * tw1g[z * 64 + n];
    TW1[(long)z * 128 * 128 + n * 128 + k] = f2b(v);
    if (k == 0)
      biasT1[z * 128 + n] =
          (n < 64) ? tw1b[z * 64 + n] * INV_BN * tw1g[z * 64 + n] + tw1be[z * 64 + n] : 0.f;
  } else if (x < 688) {  // bias0 expert part
    int i = (x - 640) * 256 + tid;  // < 12288
    if (i < 8192) bias0[i] = te0b[i] * INV_BN * te0g[i] + te0be[i];
    else {
      int r = i - 8192;
      bias0[i] = se0b[r] * INV_BN * se0g[r] + se0be[r];
    }
  } else if (x < 712) {  // bias1 expert part
    int j = (x - 688) * 256 + tid;  // < 6144
    int z = j >> 11, r = j & 2047;
    float v;
    if (z < 2) v = te1b[z * 2048 + r] * INV_BN * te1g[z * 2048 + r] + te1be[z * 2048 + r];
    else v = se1b[r] * INV_BN * se1g[r] + se1be[r];
    bias1[z * N1EXT + r] = v;
  } else {  // biasT0
    biasT0[tid] = tw0b[tid] * INV_BN * tw0g[tid] + tw0be[tid];
  }
}

// ---------------- m97-style bf16 GEMM body (round-1 staging, no swizzle) -----------
// A [M][K] bf16 row-major, Bw [N][K] bf16 (n-major), C [M][N] bf16.
// C[m][n] = (n<reluN ? relu : id)(sum_k A.B + bias[n]). 128x128 tile, BK=32.
__device__ __forceinline__ void gemm_body(
    const u16* __restrict__ A, const u16* __restrict__ Bw, u16* __restrict__ C,
    const float* __restrict__ bias, int N, int K, int reluN, int yOff) {
  __shared__ u16 As[128 * 32];
  __shared__ u16 Bs[128 * 32];
  int tid = threadIdx.x;
  int m0 = blockIdx.x * 128, n0 = (blockIdx.y + yOff) * 128;
  int l = tid & 63, w = tid >> 6;
  int wm = (w >> 1) * 64, wn = (w & 1) * 64;

  const u16* aS0 = A + (long)(m0 + (tid >> 2)) * K + (tid & 3) * 8;
  const u16* aS1 = A + (long)(m0 + 64 + (tid >> 2)) * K + (tid & 3) * 8;
  const u16* bS0 = Bw + (long)(n0 + (tid >> 2)) * K + (tid & 3) * 8;
  const u16* bS1 = Bw + (long)(n0 + 64 + (tid >> 2)) * K + (tid & 3) * 8;
  u16* aD0 = As + tid * 8;
  u16* aD1 = As + (256 + tid) * 8;
  u16* bD0 = Bs + tid * 8;
  u16* bD1 = Bs + (256 + tid) * 8;

  floatx4 acc[4][4] = {};

  int aOff[4], bOff[4];
#pragma unroll
  for (int i = 0; i < 4; i++) {
    aOff[i] = (wm + i * 16 + (l & 15)) * 32 + (l >> 4) * 8;
    bOff[i] = (wn + i * 16 + (l & 15)) * 32 + (l >> 4) * 8;
  }

  for (int k0 = 0; k0 < K; k0 += 32) {
    __builtin_amdgcn_global_load_lds((const __attribute__((address_space(1))) u16*)aS0,
                                     (__attribute__((address_space(3))) u16*)aD0, 16, 0, 0);
    __builtin_amdgcn_global_load_lds((const __attribute__((address_space(1))) u16*)aS1,
                                     (__attribute__((address_space(3))) u16*)aD1, 16, 0, 0);
    __builtin_amdgcn_global_load_lds((const __attribute__((address_space(1))) u16*)bS0,
                                     (__attribute__((address_space(3))) u16*)bD0, 16, 0, 0);
    __builtin_amdgcn_global_load_lds((const __attribute__((address_space(1))) u16*)bS1,
                                     (__attribute__((address_space(3))) u16*)bD1, 16, 0, 0);
    aS0 += 32; aS1 += 32; bS0 += 32; bS1 += 32;
    __syncthreads();
    bf16x8 af[4], bfr[4];
#pragma unroll
    for (int i = 0; i < 4; i++) af[i] = *(const bf16x8*)(As + aOff[i]);
#pragma unroll
    for (int j = 0; j < 4; j++) bfr[j] = *(const bf16x8*)(Bs + bOff[j]);
#pragma unroll
    for (int i = 0; i < 4; i++)
#pragma unroll
      for (int j = 0; j < 4; j++)
        acc[i][j] = __builtin_amdgcn_mfma_f32_16x16x32_bf16(af[i], bfr[j], acc[i][j], 0, 0, 0);
    __syncthreads();
  }

  int cn = n0 + wn + (l & 15);
  int rm = m0 + wm + ((l >> 4) << 2);
#pragma unroll
  for (int j = 0; j < 4; j++) {
    int col = cn + j * 16;
    float bv = bias[col];
    bool doRelu = col < reluN;
#pragma unroll
    for (int i = 0; i < 4; i++)
#pragma unroll
      for (int r = 0; r < 4; r++) {
        float v = acc[i][j][r] + bv;
        v = doRelu ? fmaxf(v, 0.f) : v;
        C[(long)(rm + i * 16 + r) * N + col] = f2b(v);
      }
  }
}

__global__ __launch_bounds__(256) void gemm_l0(
    const u16* __restrict__ A, const u16* __restrict__ Bw, u16* __restrict__ C,
    const float* __restrict__ bias, int yOff) {
  gemm_body(A, Bw, C, bias, N0EXT, IN0, 12288, yOff);
}

__global__ __launch_bounds__(256) void gemm_l1(
    const u16* __restrict__ A, const u16* __restrict__ Bw, u16* __restrict__ C,
    const float* __restrict__ bias) {
  int z = blockIdx.z;
  gemm_body(A + (long)z * 4096 * 512, Bw + (long)z * N1EXT * 512,
            C + (long)z * 4096 * N1EXT, bias + (long)z * N1EXT, N1EXT, 512, 2048, 0);
}

// ---------------- layer-0 softmax + mix: E0 [B][N0EXT] -> X1 [3][B][512] ----------
__global__ __launch_bounds__(256) void mix0_kernel(
    const u16* __restrict__ E0, u16* __restrict__ X1) {
  int b = blockIdx.x, tid = threadIdx.x;
  __shared__ float gw[56];
  const u16* row = E0 + (long)b * N0EXT;
  if (tid < 3) {
    int base = (tid == 0) ? 0 : (tid == 1) ? 16 : 32;
    int cnt = (tid == 2) ? 24 : 16;
    const u16* lg = row + 12288 + base;
    float mx = -1e30f;
    for (int i = 0; i < cnt; i++) mx = fmaxf(mx, b2f(lg[i]));
    float sum = 0.f;
    for (int i = 0; i < cnt; i++) {
      float e = __expf(b2f(lg[i]) - mx);
      gw[base + i] = e;
      sum += e;
    }
    float inv = 1.f / sum;
    for (int i = 0; i < cnt; i++) gw[base + i] *= inv;
  }
  __syncthreads();
#pragma unroll
  for (int half = 0; half < 2; half++) {
    int o = tid + half * 256;
    float t0 = 0.f, t1 = 0.f, s = 0.f;
#pragma unroll
    for (int e = 0; e < 8; e++) {
      float v0 = b2f(row[e * 512 + o]);
      float v1 = b2f(row[(8 + e) * 512 + o]);
      float vs = b2f(row[(16 + e) * 512 + o]);
      t0 = fmaf(gw[e], v0, t0);       t0 = fmaf(gw[8 + e], vs, t0);
      t1 = fmaf(gw[16 + e], v1, t1);  t1 = fmaf(gw[24 + e], vs, t1);
      s = fmaf(gw[32 + e], v0, s);
      s = fmaf(gw[40 + e], v1, s);
      s = fmaf(gw[48 + e], vs, s);
    }
    X1[((long)(0 * 4096 + b)) * 512 + o] = f2b(t0);
    X1[((long)(1 * 4096 + b)) * 512 + o] = f2b(t1);
    X1[((long)(2 * 4096 + b)) * 512 + o] = f2b(s);
  }
}

// ---------------- layer-1 softmax + mix: E1 [3][B][N1EXT] -> X2 [2][B][256] -------
__global__ __launch_bounds__(256) void mix1_kernel(
    const u16* __restrict__ E1, u16* __restrict__ X2) {
  int b = blockIdx.x, tid = threadIdx.x;
  __shared__ float gw[32];
  if (tid < 2) {
    const u16* lg = E1 + ((long)(tid * 4096 + b)) * N1EXT + 2048;
    float mx = -1e30f;
    for (int i = 0; i < 16; i++) mx = fmaxf(mx, b2f(lg[i]));
    float sum = 0.f;
    for (int i = 0; i < 16; i++) {
      float e = __expf(b2f(lg[i]) - mx);
      gw[tid * 16 + i] = e;
      sum += e;
    }
    float inv = 1.f / sum;
    for (int i = 0; i < 16; i++) gw[tid * 16 + i] *= inv;
  }
  __syncthreads();
  int o = tid;
  const u16* r0 = E1 + ((long)(0 * 4096 + b)) * N1EXT;
  const u16* r1 = E1 + ((long)(1 * 4096 + b)) * N1EXT;
  const u16* rs = E1 + ((long)(2 * 4096 + b)) * N1EXT;
  float t0 = 0.f, t1 = 0.f;
#pragma unroll
  for (int e = 0; e < 8; e++) {
    float vs = b2f(rs[e * 256 + o]);
    t0 = fmaf(gw[e], b2f(r0[e * 256 + o]), t0);
    t0 = fmaf(gw[8 + e], vs, t0);
    t1 = fmaf(gw[16 + e], b2f(r1[e * 256 + o]), t1);
    t1 = fmaf(gw[24 + e], vs, t1);
  }
  X2[((long)(0 * 4096 + b)) * 256 + o] = f2b(t0);
  X2[((long)(1 * 4096 + b)) * 256 + o] = f2b(t1);
}

// ---------------- fused towers: X2 --(K=256 MFMA)--> H1(LDS) --(K=128)--> H2(LDS)
// --> 64-dot + sigmoid -> out. grid (32,1,2): block = 128 rows of task z.
__global__ __launch_bounds__(256) void towers_fused(
    const u16* __restrict__ X2, const u16* __restrict__ TW0,
    const u16* __restrict__ TW1, const float* __restrict__ biasT0,
    const float* __restrict__ biasT1, const float* __restrict__ twoW,
    const float* __restrict__ twob, float* __restrict__ out) {
  __shared__ u16 As[128 * 32];
  __shared__ u16 Bs[128 * 32];
  __shared__ u16 Hs[128 * 136];  // padded rows: stride 136 u16 -> conflict-free frags
  int z = blockIdx.z;
  int tid = threadIdx.x;
  int m0 = blockIdx.x * 128;
  int l = tid & 63, w = tid >> 6;
  int wm = (w >> 1) * 64, wn = (w & 1) * 64;
  int q = l >> 4;

  const u16* A = X2 + (long)z * 4096 * 256;
  const u16* B0 = TW0 + (long)z * 128 * 256;
  const u16* B1 = TW1 + (long)z * 128 * 128;

  int aOff[4], bOff[4];
#pragma unroll
  for (int i = 0; i < 4; i++) {
    aOff[i] = (wm + i * 16 + (l & 15)) * 32 + q * 8;
    bOff[i] = (wn + i * 16 + (l & 15)) * 32 + q * 8;
  }
  int rmLoc = wm + (q << 2);
  int cnLoc = wn + (l & 15);

  // ---- tower layer 0: K=256 ----
  {
    const u16* aS0 = A + (long)(m0 + (tid >> 2)) * 256 + (tid & 3) * 8;
    const u16* aS1 = A + (long)(m0 + 64 + (tid >> 2)) * 256 + (tid & 3) * 8;
    const u16* bS0 = B0 + (long)(tid >> 2) * 256 + (tid & 3) * 8;
    const u16* bS1 = B0 + (long)(64 + (tid >> 2)) * 256 + (tid & 3) * 8;
    u16* aD0 = As + tid * 8;
    u16* aD1 = As + (256 + tid) * 8;
    u16* bD0 = Bs + tid * 8;
    u16* bD1 = Bs + (256 + tid) * 8;
    floatx4 acc[4][4] = {};
    for (int k0 = 0; k0 < 256; k0 += 32) {
      __builtin_amdgcn_global_load_lds((const __attribute__((address_space(1))) u16*)aS0,
                                       (__attribute__((address_space(3))) u16*)aD0, 16, 0, 0);
      __builtin_amdgcn_global_load_lds((const __attribute__((address_space(1))) u16*)aS1,
                                       (__attribute__((address_space(3))) u16*)aD1, 16, 0, 0);
      __builtin_amdgcn_global_load_lds((const __attribute__((address_space(1))) u16*)bS0,
                                       (__attribute__((address_space(3))) u16*)bD0, 16, 0, 0);
      __builtin_amdgcn_global_load_lds((const __attribute__((address_space(1))) u16*)bS1,
                                       (__attribute__((address_space(3))) u16*)bD1, 16, 0, 0);
      aS0 += 32; aS1 += 32; bS0 += 32; bS1 += 32;
      __syncthreads();
      bf16x8 af[4], bfr[4];
#pragma unroll
      for (int i = 0; i < 4; i++) af[i] = *(const bf16x8*)(As + aOff[i]);
#pragma unroll
      for (int j = 0; j < 4; j++) bfr[j] = *(const bf16x8*)(Bs + bOff[j]);
#pragma unroll
      for (int i = 0; i < 4; i++)
#pragma unroll
        for (int j = 0; j < 4; j++)
          acc[i][j] = __builtin_amdgcn_mfma_f32_16x16x32_bf16(af[i], bfr[j], acc[i][j], 0, 0, 0);
      __syncthreads();
    }
    // H1 -> LDS (relu + bias)
#pragma unroll
    for (int j = 0; j < 4; j++) {
      int col = cnLoc + j * 16;
      float bv = biasT0[z * 128 + col];
#pragma unroll
      for (int i = 0; i < 4; i++)
#pragma unroll
        for (int r = 0; r < 4; r++)
          Hs[(rmLoc + i * 16 + r) * 136 + col] = f2b(fmaxf(acc[i][j][r] + bv, 0.f));
    }
  }
  __syncthreads();

  // ---- tower layer 1: K=128, A from Hs ----
  floatx4 acc2[4][4] = {};
  {
    const u16* bS0 = B1 + (long)(tid >> 2) * 128 + (tid & 3) * 8;
    const u16* bS1 = B1 + (long)(64 + (tid >> 2)) * 128 + (tid & 3) * 8;
    u16* bD0 = Bs + tid * 8;
    u16* bD1 = Bs + (256 + tid) * 8;
    for (int k0 = 0; k0 < 128; k0 += 32) {
      __builtin_amdgcn_global_load_lds((const __attribute__((address_space(1))) u16*)bS0,
                                       (__attribute__((address_space(3))) u16*)bD0, 16, 0, 0);
      __builtin_amdgcn_global_load_lds((const __attribute__((address_space(1))) u16*)bS1,
                                       (__attribute__((address_space(3))) u16*)bD1, 16, 0, 0);
      bS0 += 32; bS1 += 32;
      __syncthreads();
      bf16x8 af[4], bfr[4];
#pragma unroll
      for (int i = 0; i < 4; i++)
        af[i] = *(const bf16x8*)(Hs + (wm + i * 16 + (l & 15)) * 136 + k0 + q * 8);
#pragma unroll
      for (int j = 0; j < 4; j++) bfr[j] = *(const bf16x8*)(Bs + bOff[j]);
#pragma unroll
      for (int i = 0; i < 4; i++)
#pragma unroll
        for (int j = 0; j < 4; j++)
          acc2[i][j] = __builtin_amdgcn_mfma_f32_16x16x32_bf16(af[i], bfr[j], acc2[i][j], 0, 0, 0);
      __syncthreads();
    }
  }
  // H2 -> LDS (relu + bias)
#pragma unroll
  for (int j = 0; j < 4; j++) {
    int col = cnLoc + j * 16;
    float bv = biasT1[z * 128 + col];
#pragma unroll
    for (int i = 0; i < 4; i++)
#pragma unroll
      for (int r = 0; r < 4; r++)
        Hs[(rmLoc + i * 16 + r) * 136 + col] = f2b(fmaxf(acc2[i][j][r] + bv, 0.f));
  }
  __syncthreads();

  // ---- final 64-dot + sigmoid ----
  if (tid < 128) {
    const float* wc = twoW + z * 64;
    const u16* xr = Hs + tid * 136;
    float acc = twob[z];
    for (int k = 0; k < 64; k++) acc = fmaf(b2f(xr[k]), wc[k], acc);
    out[z * 4096 + m0 + tid] = 1.f / (1.f + __expf(-acc));
  }
}

extern "C" void kernel_launch(void* const* d_in, const int* in_sizes, int n_in,
                              void* d_out, int out_size, void* d_ws, size_t ws_size,
                              hipStream_t stream) {
  const int* cat = (const int*)d_in[0];
  const float* numx = (const float*)d_in[1];
  const float* table = (const float*)d_in[2];
  const float* numW = (const float*)d_in[3];
  const float* numb = (const float*)d_in[4];
  const float* se0W = (const float*)d_in[5];
  const float* se0b = (const float*)d_in[6];
  const float* se0g = (const float*)d_in[7];
  const float* se0be = (const float*)d_in[8];
  const float* te0W = (const float*)d_in[9];
  const float* te0b = (const float*)d_in[10];
  const float* te0g = (const float*)d_in[11];
  const float* te0be = (const float*)d_in[12];
  const float* tg0W = (const float*)d_in[13];
  const float* tg0b = (const float*)d_in[14];
  const float* sg0W = (const float*)d_in[15];
  const float* sg0b = (const float*)d_in[16];
  const float* se1W = (const float*)d_in[17];
  const float* se1b = (const float*)d_in[18];
  const float* se1g = (const float*)d_in[19];
  const float* se1be = (const float*)d_in[20];
  const float* te1W = (const float*)d_in[21];
  const float* te1b = (const float*)d_in[22];
  const float* te1g = (const float*)d_in[23];
  const float* te1be = (const float*)d_in[24];
  const float* tg1W = (const float*)d_in[25];
  const float* tg1b = (const float*)d_in[26];
  const float* tw0W = (const float*)d_in[27];
  const float* tw0b = (const float*)d_in[28];
  const float* tw0g = (const float*)d_in[29];
  const float* tw0be = (const float*)d_in[30];
  const float* tw1W = (const float*)d_in[31];
  const float* tw1b = (const float*)d_in[32];
  const float* tw1g = (const float*)d_in[33];
  const float* tw1be = (const float*)d_in[34];
  const float* twoW = (const float*)d_in[35];
  const float* twob = (const float*)d_in[36];
  float* out = (float*)d_out;

  char* p = (char*)d_ws;
  u16* X0 = (u16*)p;        p += (size_t)4096 * IN0 * 2;
  u16* W0 = (u16*)p;        p += (size_t)N0EXT * IN0 * 2;
  float* bias0 = (float*)p; p += (size_t)N0EXT * 4;
  u16* X1 = (u16*)p;        p += (size_t)3 * 4096 * 512 * 2;
  u16* W1 = (u16*)p;        p += (size_t)3 * N1EXT * 512 * 2;
  float* bias1 = (float*)p; p += (size_t)3 * N1EXT * 4;
  u16* X2 = (u16*)p;        p += (size_t)2 * 4096 * 256 * 2;
  u16* TW0 = (u16*)p;       p += (size_t)2 * 128 * 256 * 2;
  float* biasT0 = (float*)p; p += (size_t)256 * 4;
  u16* TW1 = (u16*)p;       p += (size_t)2 * 128 * 128 * 2;
  float* biasT1 = (float*)p; p += (size_t)256 * 4;
  // big region, reused across phases: E0 -> E1
  u16* E0 = (u16*)p;  // 4096*N0EXT
  u16* E1 = (u16*)p;  // 3*4096*N1EXT  (E0 dead after mix0)

  input_build<<<10240, 256, 0, stream>>>(cat, table, numx, numW, numb, X0);
  repack_w_all<<<dim3(68, 16, 50), 256, 0, stream>>>(
      te0W, te0g, se0W, se0g, te1W, te1g, se1W, se1g, tw0W, tw0g, W0, W1, TW0);
  setup_small<<<713, 256, 0, stream>>>(
      tg0W, tg0b, sg0W, sg0b, tg1W, tg1b,
      te0b, te0g, te0be, se0b, se0g, se0be,
      te1b, te1g, te1be, se1b, se1g, se1be,
      tw0b, tw0g, tw0be, tw1W, tw1b, tw1g, tw1be,
      W0, W1, TW1, bias0, bias1, biasT0, biasT1);

  // PLE layer 0 GEMM split in two halves (profiling granularity)
  gemm_l0<<<dim3(32, 49), 256, 0, stream>>>(X0, W0, E0, bias0, 0);
  gemm_l0<<<dim3(32, 48), 256, 0, stream>>>(X0, W0, E0, bias0, 49);
  mix0_kernel<<<4096, 256, 0, stream>>>(E0, X1);

  gemm_l1<<<dim3(32, 17, 3), 256, 0, stream>>>(X1, W1, E1, bias1);
  mix1_kernel<<<4096, 256, 0, stream>>>(E1, X2);

  towers_fused<<<dim3(32, 1, 2), 256, 0, stream>>>(
      X2, TW0, TW1, biasT0, biasT1, twoW, twob, out);
}